// Round 2
// 482.719 us; speedup vs baseline: 1.0097x; 1.0097x over previous
//
#include <hip/hip_runtime.h>
#include <hip/hip_bf16.h>
#include <stdint.h>

#define NN 50000
#define NE 600000
#define IN_DIM 512
#define HID 128
#define ODIM 64
#define EPSV 0.1f
#define NBLK ((NN + 255) / 256)  // 196 scan blocks

typedef __attribute__((ext_vector_type(8))) short short8;
typedef __attribute__((ext_vector_type(4))) float f32x4;

__device__ __forceinline__ ushort f2bf(float f) {
    union { float f; uint32_t i; } v; v.f = f;
    uint32_t lsb = (v.i >> 16) & 1u;
    uint32_t r = v.i + 0x7fffu + lsb;
    return (ushort)(r >> 16);
}

__device__ __forceinline__ short8 pack8(float4 lo, float4 hi) {
    short8 r;
    r[0] = (short)f2bf(lo.x); r[1] = (short)f2bf(lo.y);
    r[2] = (short)f2bf(lo.z); r[3] = (short)f2bf(lo.w);
    r[4] = (short)f2bf(hi.x); r[5] = (short)f2bf(hi.y);
    r[6] = (short)f2bf(hi.z); r[7] = (short)f2bf(hi.w);
    return r;
}

// fast tanh: (e^2z - 1) / (e^2z + 1), clamped
__device__ __forceinline__ float fast_tanh(float z) {
    z = fminf(fmaxf(z, -15.f), 15.f);
    float t = __expf(2.f * z);
    return __fdividef(t - 1.f, t + 1.f);
}

// ---- degree count ----
__global__ __launch_bounds__(256) void deg_kernel(const int* __restrict__ dst, int* __restrict__ deg) {
    int e = blockIdx.x * 256 + threadIdx.x;
    if (e < NE) atomicAdd(&deg[dst[e]], 1);
}

// ---- scan phase A ----
__global__ __launch_bounds__(256) void scanA_kernel(const int* __restrict__ deg,
                                                    int* __restrict__ localScan,
                                                    int* __restrict__ blockSums,
                                                    float* __restrict__ dinv) {
    __shared__ int tmp[256];
    int t = threadIdx.x;
    int i = blockIdx.x * 256 + t;
    int v = (i < NN) ? deg[i] : 0;
    tmp[t] = v;
    __syncthreads();
    for (int off = 1; off < 256; off <<= 1) {
        int add = (t >= off) ? tmp[t - off] : 0;
        __syncthreads();
        tmp[t] += add;
        __syncthreads();
    }
    if (i < NN) {
        localScan[i] = tmp[t] - v;
        dinv[i] = (v > 0) ? (1.0f / sqrtf((float)v)) : 0.0f;
    }
    if (t == 255) blockSums[blockIdx.x] = tmp[255];
}

// ---- scan phase B ----
__global__ __launch_bounds__(256) void scanB_kernel(const int* __restrict__ blockSums,
                                                    int* __restrict__ blockOff) {
    __shared__ int tmp[256];
    int t = threadIdx.x;
    int v = (t < NBLK) ? blockSums[t] : 0;
    tmp[t] = v;
    __syncthreads();
    for (int off = 1; off < 256; off <<= 1) {
        int add = (t >= off) ? tmp[t - off] : 0;
        __syncthreads();
        tmp[t] += add;
        __syncthreads();
    }
    blockOff[t] = tmp[t] - v;
}

// ---- scan phase C ----
__global__ __launch_bounds__(256) void scanC_kernel(const int* __restrict__ localScan,
                                                    const int* __restrict__ blockOff,
                                                    int* __restrict__ rowptr,
                                                    int* __restrict__ cursor) {
    int i = blockIdx.x * 256 + threadIdx.x;
    if (i < NN) {
        int v = localScan[i] + blockOff[blockIdx.x];
        rowptr[i] = v;
        cursor[i] = v;
    }
    if (i == 0) rowptr[NN] = NE;
}

// ---- fill CSR ----
__global__ __launch_bounds__(256) void fill_kernel(const int* __restrict__ src, const int* __restrict__ dst,
                                                   int* __restrict__ cursor, int* __restrict__ csr_src) {
    int e = blockIdx.x * 256 + threadIdx.x;
    if (e < NE) {
        int d = dst[e];
        int slot = atomicAdd(&cursor[d], 1);
        csr_src[slot] = src[e];
    }
}

// ---- convert W1 fp32 -> bf16 ----
__global__ __launch_bounds__(256) void cvtw_kernel(const float* __restrict__ w, ushort* __restrict__ wbf) {
    int i = blockIdx.x * 256 + threadIdx.x;
    if (i < HID * IN_DIM) wbf[i] = f2bf(w[i]);
}

// ---- h0 = relu(x @ W1^T + b1), fused layer-0 attention scalars ----
// Barrier-free: one wave owns 16 rows (50000/16 = 3125 waves exactly). A is
// streamed global->reg with depth-2 prefetch (fully unrolled K loop, offsets
// fold into load imm), converted with the same f2bf as before (bit-identical
// h0), B read straight from L2-resident wbf (128 KB). No LDS, no barriers ->
// loads issue continuously instead of in barrier-aligned bursts.
// Epilogue also computes AD/AR for layer 0 (row lives inside one wave).
__global__ __launch_bounds__(256, 4) void gemm1_kernel(const float* __restrict__ x,
                                                       const ushort* __restrict__ wbf,
                                                       const float* __restrict__ b,
                                                       const float* __restrict__ attl,
                                                       const float* __restrict__ attr,
                                                       const float* __restrict__ dinv,
                                                       float* __restrict__ h,
                                                       float2* __restrict__ AD,
                                                       float* __restrict__ AR) {
    int t = threadIdx.x;
    int wv = __builtin_amdgcn_readfirstlane(t >> 6);
    int lane = t & 63;
    int wid = blockIdx.x * 4 + wv;
    if (wid >= NN / 16) return;

    int rsel = lane & 15;          // A row within stripe / B row select
    int koff = (lane >> 4) * 8;    // K sub-offset within 32-wide MFMA step
    int row = wid * 16 + rsel;

    const float*  xr  = x + (size_t)row * IN_DIM + koff;
    const ushort* wp0 = wbf + (size_t)rsel * IN_DIM + koff;

    f32x4 acc[8];
#pragma unroll
    for (int tt = 0; tt < 8; ++tt) acc[tt] = (f32x4){0.f, 0.f, 0.f, 0.f};

    // depth-2 prefetch: two K-steps (2 x 8 floats/lane) in flight
    float4 c0lo = *(const float4*)(xr);
    float4 c0hi = *(const float4*)(xr + 4);
    float4 c1lo = *(const float4*)(xr + 32);
    float4 c1hi = *(const float4*)(xr + 36);

#pragma unroll
    for (int ks = 0; ks < 16; ks += 2) {
        float4 n0lo, n0hi, n1lo, n1hi;
        bool more = (ks + 2 < 16);
        if (more) {
            n0lo = *(const float4*)(xr + (ks + 2) * 32);
            n0hi = *(const float4*)(xr + (ks + 2) * 32 + 4);
            n1lo = *(const float4*)(xr + (ks + 3) * 32);
            n1hi = *(const float4*)(xr + (ks + 3) * 32 + 4);
        }
        short8 a0 = pack8(c0lo, c0hi);
#pragma unroll
        for (int tt = 0; tt < 8; ++tt) {
            short8 bf = *(const short8*)(wp0 + (size_t)tt * 16 * IN_DIM + ks * 32);
            acc[tt] = __builtin_amdgcn_mfma_f32_16x16x32_bf16(a0, bf, acc[tt], 0, 0, 0);
        }
        short8 a1 = pack8(c1lo, c1hi);
#pragma unroll
        for (int tt = 0; tt < 8; ++tt) {
            short8 bf = *(const short8*)(wp0 + (size_t)tt * 16 * IN_DIM + (ks + 1) * 32);
            acc[tt] = __builtin_amdgcn_mfma_f32_16x16x32_bf16(a1, bf, acc[tt], 0, 0, 0);
        }
        if (more) { c0lo = n0lo; c0hi = n0hi; c1lo = n1lo; c1hi = n1hi; }
    }

    // epilogue: bias + relu + store + fused layer-0 attention scalars
    int rbase = (lane >> 4) * 4;
    int col0 = lane & 15;
    float alv[8], arv[8], bias[8];
#pragma unroll
    for (int tt = 0; tt < 8; ++tt) {
        alv[tt]  = attl[tt * 16 + col0];
        arv[tt]  = attr[tt * 16 + col0];
        bias[tt] = b[tt * 16 + col0];
    }
#pragma unroll
    for (int r = 0; r < 4; ++r) {
        int rrow = wid * 16 + rbase + r;
        float p = 0.f, q = 0.f;
#pragma unroll
        for (int tt = 0; tt < 8; ++tt) {
            float v = acc[tt][r] + bias[tt];
            v = v > 0.f ? v : 0.f;
            h[(size_t)rrow * HID + tt * 16 + col0] = v;
            p += v * alv[tt];
            q += v * arv[tt];
        }
#pragma unroll
        for (int off = 8; off; off >>= 1) { p += __shfl_xor(p, off); q += __shfl_xor(q, off); }
        if (col0 == 0) {
            float2 vv; vv.x = p; vv.y = dinv[rrow];
            AD[rrow] = vv;
            AR[rrow] = q;
        }
    }
}

// ---- FAConv aggregation: wave per dst node ----
__global__ __launch_bounds__(256) void agg_kernel(const float* __restrict__ h,
                                                  const float* __restrict__ raw,
                                                  float* __restrict__ hn,
                                                  const int* __restrict__ rowptr,
                                                  const int* __restrict__ csr_src,
                                                  const float* __restrict__ dinv,
                                                  const float2* __restrict__ AD,
                                                  const float* __restrict__ AR,
                                                  const float* __restrict__ attl_next,
                                                  const float* __restrict__ attr_next,
                                                  float2* __restrict__ ADout,
                                                  float* __restrict__ ARout) {
    int wv = __builtin_amdgcn_readfirstlane(threadIdx.x >> 6);
    int lane = threadIdx.x & 63;
    int d = blockIdx.x * 4 + wv;
    if (d >= NN) return;
    const float2* h2 = (const float2*)h;
    float ar_d = AR[d];
    float dinv_d = dinv[d];
    float2 rawd = ((const float2*)raw)[(size_t)d * 64 + lane];
    float accx = EPSV * rawd.x, accy = EPSV * rawd.y;
    int e = rowptr[d], e1 = rowptr[d + 1];
    for (; e + 4 <= e1; e += 4) {
        int s0 = __builtin_amdgcn_readfirstlane(csr_src[e]);
        int s1 = __builtin_amdgcn_readfirstlane(csr_src[e + 1]);
        int s2 = __builtin_amdgcn_readfirstlane(csr_src[e + 2]);
        int s3 = __builtin_amdgcn_readfirstlane(csr_src[e + 3]);
        float2 ad0 = AD[s0], ad1 = AD[s1], ad2 = AD[s2], ad3 = AD[s3];
        float2 v0 = h2[(size_t)s0 * 64 + lane];
        float2 v1 = h2[(size_t)s1 * 64 + lane];
        float2 v2 = h2[(size_t)s2 * 64 + lane];
        float2 v3 = h2[(size_t)s3 * 64 + lane];
        float w0 = fast_tanh(ad0.x + ar_d) * ad0.y * dinv_d;
        float w1 = fast_tanh(ad1.x + ar_d) * ad1.y * dinv_d;
        float w2 = fast_tanh(ad2.x + ar_d) * ad2.y * dinv_d;
        float w3 = fast_tanh(ad3.x + ar_d) * ad3.y * dinv_d;
        accx += w0 * v0.x + w1 * v1.x + w2 * v2.x + w3 * v3.x;
        accy += w0 * v0.y + w1 * v1.y + w2 * v2.y + w3 * v3.y;
    }
    for (; e < e1; ++e) {
        int s = __builtin_amdgcn_readfirstlane(csr_src[e]);
        float2 ad = AD[s];
        float2 v = h2[(size_t)s * 64 + lane];
        float w = fast_tanh(ad.x + ar_d) * ad.y * dinv_d;
        accx += w * v.x;
        accy += w * v.y;
    }
    float2 o; o.x = accx; o.y = accy;
    ((float2*)hn)[(size_t)d * 64 + lane] = o;
    if (attl_next) {
        float al0 = attl_next[2 * lane], al1 = attl_next[2 * lane + 1];
        float ar0 = attr_next[2 * lane], ar1 = attr_next[2 * lane + 1];
        float p = accx * al0 + accy * al1;
        float q = accx * ar0 + accy * ar1;
#pragma unroll
        for (int off = 32; off; off >>= 1) { p += __shfl_xor(p, off); q += __shfl_xor(q, off); }
        if (lane == 0) {
            float2 v; v.x = p; v.y = dinv_d;
            ADout[d] = v;
            ARout[d] = q;
        }
    }
}

// ---- head: emb = h @ W2^T + b2; out0 = log_softmax(emb); out1 = emb ----
__global__ __launch_bounds__(256) void head_kernel(const float* __restrict__ h,
                                                   const float* __restrict__ w2,
                                                   const float* __restrict__ b2,
                                                   float* __restrict__ out) {
    __shared__ float w2t[HID * 65];
    int t = threadIdx.x;
    for (int i = t; i < HID * ODIM; i += 256) {
        int j = i >> 7, k = i & 127;
        w2t[k * 65 + j] = w2[i];
    }
    __syncthreads();
    int lane = t & 63;
    int wv = __builtin_amdgcn_readfirstlane(t >> 6);
    int d = blockIdx.x * 4 + wv;
    if (d >= NN) return;
    const float* hr = h + (size_t)d * HID;
    float ea = b2[lane], eb = 0.f;
#pragma unroll 8
    for (int k = 0; k < HID; k += 2) {
        ea += hr[k] * w2t[k * 65 + lane];
        eb += hr[k + 1] * w2t[(k + 1) * 65 + lane];
    }
    float e = ea + eb;
    float m = e;
#pragma unroll
    for (int off = 32; off; off >>= 1) m = fmaxf(m, __shfl_xor(m, off));
    float ex = __expf(e - m);
    float s = ex;
#pragma unroll
    for (int off = 32; off; off >>= 1) s += __shfl_xor(s, off);
    float lsm = e - m - __logf(s);
    out[(size_t)d * ODIM + lane] = lsm;
    out[(size_t)NN * ODIM + (size_t)d * ODIM + lane] = e;
}

extern "C" void kernel_launch(void* const* d_in, const int* in_sizes, int n_in,
                              void* d_out, int out_size, void* d_ws, size_t ws_size,
                              hipStream_t stream) {
    const float* x    = (const float*)d_in[0];
    const int*   ei   = (const int*)d_in[1];
    const float* t1w  = (const float*)d_in[2];
    const float* t1b  = (const float*)d_in[3];
    const float* t2w  = (const float*)d_in[4];
    const float* t2b  = (const float*)d_in[5];
    const float* attl = (const float*)d_in[6];
    const float* attr = (const float*)d_in[7];
    float* out = (float*)d_out;

    const int* src = ei;
    const int* dst = ei + NE;

    char* ws = (char*)d_ws;
    size_t off = 0;
    auto alloc = [&](size_t bytes) { char* p = ws + off; off += (bytes + 255) & ~(size_t)255; return p; };
    float*  hA   = (float*)alloc((size_t)NN * HID * 4); // raw / h0
    float*  hB   = (float*)alloc((size_t)NN * HID * 4);
    float*  hC   = (float*)alloc((size_t)NN * HID * 4);
    ushort* wbf  = (ushort*)alloc((size_t)HID * IN_DIM * 2);
    int*    deg  = (int*)alloc((size_t)NN * 4);
    float*  dinv = (float*)alloc((size_t)NN * 4);
    int*    rowptr = (int*)alloc((size_t)(NN + 1) * 4);
    int*    cursor = (int*)alloc((size_t)NN * 4);
    int*    csr_src = (int*)alloc((size_t)NE * 4);
    int*    localScan = (int*)alloc((size_t)NN * 4);
    int*    blockSums = (int*)alloc((size_t)256 * 4);
    int*    blockOff  = (int*)alloc((size_t)256 * 4);
    float2* AD_A = (float2*)alloc((size_t)NN * 8);
    float*  AR_A = (float*)alloc((size_t)NN * 4);
    float2* AD_B = (float2*)alloc((size_t)NN * 8);
    float*  AR_B = (float*)alloc((size_t)NN * 4);
    (void)ws_size;

    hipMemsetAsync(deg, 0, (size_t)NN * 4, stream);

    dim3 blk(256);
    deg_kernel<<<(NE + 255) / 256, blk, 0, stream>>>(dst, deg);
    scanA_kernel<<<NBLK, blk, 0, stream>>>(deg, localScan, blockSums, dinv);
    scanB_kernel<<<1, blk, 0, stream>>>(blockSums, blockOff);
    scanC_kernel<<<NBLK, blk, 0, stream>>>(localScan, blockOff, rowptr, cursor);
    fill_kernel<<<(NE + 255) / 256, blk, 0, stream>>>(src, dst, cursor, csr_src);

    cvtw_kernel<<<(HID * IN_DIM + 255) / 256, blk, 0, stream>>>(t1w, wbf);
    // 3125 waves of 16 rows each, 4 waves/block -> 782 blocks; fused att0
    gemm1_kernel<<<(NN / 16 + 3) / 4, blk, 0, stream>>>(x, wbf, t1b,
                                                        attl + 0 * HID, attr + 0 * HID,
                                                        dinv, hA, AD_A, AR_A);

    // L0: hA -> hB, epilogue computes layer-1 scalars into AD_B/AR_B
    agg_kernel<<<(NN + 3) / 4, blk, 0, stream>>>(hA, hA, hB, rowptr, csr_src, dinv,
                                                 AD_A, AR_A, attl + 1 * HID, attr + 1 * HID, AD_B, AR_B);
    // L1: hB -> hC, epilogue computes layer-2 scalars into AD_A/AR_A
    agg_kernel<<<(NN + 3) / 4, blk, 0, stream>>>(hB, hA, hC, rowptr, csr_src, dinv,
                                                 AD_B, AR_B, attl + 2 * HID, attr + 2 * HID, AD_A, AR_A);
    // L2: hC -> hB, no epilogue
    agg_kernel<<<(NN + 3) / 4, blk, 0, stream>>>(hC, hA, hB, rowptr, csr_src, dinv,
                                                 AD_A, AR_A, nullptr, nullptr, nullptr, nullptr);

    head_kernel<<<(NN + 3) / 4, blk, 0, stream>>>(hB, t2w, t2b, out);
}